// Round 1
// baseline (1663.427 us; speedup 1.0000x reference)
//
#include <hip/hip_runtime.h>
#include <cstdint>
#include <math.h>

#define BB 16
#define NN 2048
#define EE 32768
#define FIN 32
#define HH 128
#define KK1 1639
#define KK2 1312
#define KK3 1050

// ---------------- layer-1 edge aggregation (F=32), all edges valid ----------------
__global__ void agg1_kernel(const float* __restrict__ x,
                            const int* __restrict__ ei,
                            float* __restrict__ agg) {
    int t = blockIdx.x * blockDim.x + threadIdx.x;   // B*E*8 threads (float4 chunks)
    int c = t & 7;
    int e = (t >> 3) & (EE - 1);
    int b = t >> 18;                                  // E*8 = 2^18
    if (b >= BB) return;
    int s = ei[b * 2 * EE + e];
    int d = ei[b * 2 * EE + EE + e];
    const float4 v = *reinterpret_cast<const float4*>(x + ((size_t)(b * NN + s)) * FIN + c * 4);
    float* ap = agg + ((size_t)(b * NN + d)) * FIN + c * 4;
    atomicAdd(ap + 0, v.x); atomicAdd(ap + 1, v.y);
    atomicAdd(ap + 2, v.z); atomicAdd(ap + 3, v.w);
}

// ---------------- layer-2/3 edge aggregation (F=128), -1 = invalid ----------------
__global__ void agg23_kernel(const float* __restrict__ x,
                             const int* __restrict__ cs,
                             const int* __restrict__ cd,
                             float* __restrict__ agg) {
    int t = blockIdx.x * blockDim.x + threadIdx.x;   // B*E*32 threads
    int c = t & 31;
    int e = (t >> 5) & (EE - 1);
    int b = t >> 20;                                  // E*32 = 2^20
    if (b >= BB) return;
    int s = cs[b * EE + e];
    if (s < 0) return;
    int d = cd[b * EE + e];
    const float4 v = *reinterpret_cast<const float4*>(x + ((size_t)(b * NN + s)) * HH + c * 4);
    float* ap = agg + ((size_t)(b * NN + d)) * HH + c * 4;
    atomicAdd(ap + 0, v.x); atomicAdd(ap + 1, v.y);
    atomicAdd(ap + 2, v.z); atomicAdd(ap + 3, v.w);
}

// ---------------- conv1: h = relu(x@Wr^T + agg@Wl^T + b), F_IN=32 -> H=128 ----------------
__global__ __launch_bounds__(128) void conv1_kernel(
    const float* __restrict__ x, const float* __restrict__ agg,
    const float* __restrict__ Wroot, const float* __restrict__ Wrel,
    const float* __restrict__ bias, float* __restrict__ h) {
    __shared__ float sx[8 * FIN];
    __shared__ float sa[8 * FIN];
    int b = blockIdx.y;
    int r0 = blockIdx.x * 8;
    int tid = threadIdx.x;
    size_t base = ((size_t)b * NN + r0) * FIN;
    for (int idx = tid; idx < 8 * FIN; idx += 128) { sx[idx] = x[base + idx]; sa[idx] = agg[base + idx]; }
    __syncthreads();
    int o = tid;
    float acc[8];
#pragma unroll
    for (int r = 0; r < 8; r++) acc[r] = bias[o];
    for (int j = 0; j < FIN; j += 4) {
        float4 wr = *reinterpret_cast<const float4*>(Wroot + o * FIN + j);
        float4 wl = *reinterpret_cast<const float4*>(Wrel + o * FIN + j);
#pragma unroll
        for (int r = 0; r < 8; r++) {
            float4 xv = *reinterpret_cast<const float4*>(sx + r * FIN + j);
            float4 av = *reinterpret_cast<const float4*>(sa + r * FIN + j);
            acc[r] += xv.x * wr.x + xv.y * wr.y + xv.z * wr.z + xv.w * wr.w
                    + av.x * wl.x + av.y * wl.y + av.z * wl.z + av.w * wl.w;
        }
    }
    size_t ob = ((size_t)b * NN + r0) * HH + o;
#pragma unroll
    for (int r = 0; r < 8; r++) h[ob + (size_t)r * HH] = fmaxf(acc[r], 0.f);
}

// ---------------- conv2/3: H=128 -> H=128, 16 rows per block ----------------
__global__ __launch_bounds__(128) void conv23_kernel(
    const float* __restrict__ x, const float* __restrict__ agg,
    const float* __restrict__ Wroot, const float* __restrict__ Wrel,
    const float* __restrict__ bias, float* __restrict__ h, int n) {
    __shared__ float sx[16 * HH];
    __shared__ float sa[16 * HH];
    int b = blockIdx.y;
    int r0 = blockIdx.x * 16;
    int tid = threadIdx.x;
    size_t base = ((size_t)b * NN + r0) * HH;
    for (int idx = tid; idx < 16 * HH; idx += 128) { sx[idx] = x[base + idx]; sa[idx] = agg[base + idx]; }
    __syncthreads();
    int o = tid;
    float acc[16];
#pragma unroll
    for (int r = 0; r < 16; r++) acc[r] = bias[o];
    for (int j = 0; j < HH; j += 4) {
        float4 wr = *reinterpret_cast<const float4*>(Wroot + o * HH + j);
        float4 wl = *reinterpret_cast<const float4*>(Wrel + o * HH + j);
#pragma unroll
        for (int r = 0; r < 16; r++) {
            float4 xv = *reinterpret_cast<const float4*>(sx + r * HH + j);
            float4 av = *reinterpret_cast<const float4*>(sa + r * HH + j);
            acc[r] += xv.x * wr.x + xv.y * wr.y + xv.z * wr.z + xv.w * wr.w
                    + av.x * wl.x + av.y * wl.y + av.z * wl.z + av.w * wl.w;
        }
    }
#pragma unroll
    for (int r = 0; r < 16; r++) {
        int i = r0 + r;
        if (i < n) h[((size_t)b * NN + i) * HH + o] = fmaxf(acc[r], 0.f);
    }
}

// ---------------- per-graph: scores + full stable descending sort + perm/vals/inv ----------------
__global__ __launch_bounds__(1024) void pool_sort_kernel(
    const float* __restrict__ h, const float* __restrict__ p,
    int n, int k, int* __restrict__ perm, float* __restrict__ vals,
    int* __restrict__ inv) {
    __shared__ unsigned long long keys[NN];
    __shared__ float ssc[NN];
    __shared__ float sp[HH];
    __shared__ float snorm;
    int b = blockIdx.x, tid = threadIdx.x;
    if (tid < HH) sp[tid] = p[tid];
    __syncthreads();
    if (tid == 0) {
        float s = 0.f;
        for (int j = 0; j < HH; j++) s += sp[j] * sp[j];
        snorm = sqrtf(s);
    }
    __syncthreads();
    int wave = tid >> 6, lane = tid & 63;
    for (int i = wave; i < n; i += 16) {
        const float* row = h + ((size_t)b * NN + i) * HH;
        float v = row[lane] * sp[lane] + row[lane + 64] * sp[lane + 64];
#pragma unroll
        for (int off = 32; off; off >>= 1) v += __shfl_xor(v, off);
        if (lane == 0) ssc[i] = tanhf(v / snorm);
    }
    __syncthreads();
    for (int i = tid; i < NN; i += 1024) {
        unsigned long long key;
        if (i < n) {
            unsigned u = __float_as_uint(ssc[i]);
            u = (u & 0x80000000u) ? ~u : (u ^ 0x80000000u);   // monotone ascending
            u = ~u;                                            // -> descending
            key = ((unsigned long long)u << 32) | (unsigned)i; // ties: low index first
        } else {
            key = ~0ULL;
        }
        keys[i] = key;
    }
    __syncthreads();
    // bitonic sort, ascending keys
    for (int kk = 2; kk <= NN; kk <<= 1) {
        for (int j = kk >> 1; j > 0; j >>= 1) {
            for (int i = tid; i < NN; i += 1024) {
                int l = i ^ j;
                if (l > i) {
                    unsigned long long a = keys[i], c = keys[l];
                    bool up = ((i & kk) == 0);
                    if ((a > c) == up) { keys[i] = c; keys[l] = a; }
                }
            }
            __syncthreads();
        }
    }
    for (int i = tid; i < n; i += 1024) inv[b * NN + i] = -1;
    __syncthreads();
    for (int i = tid; i < k; i += 1024) {
        int pi = (int)(keys[i] & 0xFFFFFFFFu);
        perm[b * NN + i] = pi;
        vals[b * NN + i] = ssc[pi];
        inv[b * NN + pi] = i;
    }
}

// ---------------- x_new[i] = h[perm[i]] * vals[i] ----------------
__global__ void gather_kernel(const float* __restrict__ hin,
                              float* __restrict__ xout,
                              const int* __restrict__ perm,
                              const float* __restrict__ vals, int k) {
    int t = blockIdx.x * blockDim.x + threadIdx.x;
    int total = BB * k * 32;
    if (t >= total) return;
    int c = t & 31;
    int rem = t >> 5;
    int i = rem % k;
    int b = rem / k;
    int pi = perm[b * NN + i];
    float v = vals[b * NN + i];
    float4 x4 = *reinterpret_cast<const float4*>(hin + ((size_t)b * NN + pi) * HH + c * 4);
    float4 o4 = make_float4(x4.x * v, x4.y * v, x4.z * v, x4.w * v);
    *reinterpret_cast<float4*>(xout + ((size_t)b * NN + i) * HH + c * 4) = o4;
}

// ---------------- readout: stage 1 partials (16 blocks/graph) ----------------
__global__ __launch_bounds__(128) void readout_part_kernel(
    const float* __restrict__ x, int k, float* __restrict__ part) {
    int b = blockIdx.x >> 4;
    int j = blockIdx.x & 15;
    int f = threadIdx.x;
    float mx = -INFINITY, sm = 0.f;
    for (int i = j; i < k; i += 16) {
        float v = x[((size_t)b * NN + i) * HH + f];
        mx = fmaxf(mx, v);
        sm += v;
    }
    part[(size_t)blockIdx.x * 256 + f] = mx;
    part[(size_t)blockIdx.x * 256 + 128 + f] = sm;
}

// ---------------- readout: combine + accumulate into r ----------------
__global__ __launch_bounds__(128) void readout_comb_kernel(
    const float* __restrict__ part, float* __restrict__ r, int k) {
    int b = blockIdx.x;
    int f = threadIdx.x;
    float mx = -INFINITY, sm = 0.f;
    for (int j = 0; j < 16; j++) {
        mx = fmaxf(mx, part[((size_t)b * 16 + j) * 256 + f]);
        sm += part[((size_t)b * 16 + j) * 256 + 128 + f];
    }
    r[b * 256 + f] += mx;
    r[b * 256 + 128 + f] += sm / (float)k;
}

// ---------------- edge remap through inv; -1 marks invalid ----------------
__global__ void remap_kernel(const int* __restrict__ inv,
                             const int* __restrict__ sin_,
                             const int* __restrict__ din_,
                             int in_stride,
                             int* __restrict__ sout, int* __restrict__ dout) {
    int t = blockIdx.x * blockDim.x + threadIdx.x;   // B*E
    int e = t & (EE - 1);
    int b = t >> 15;
    if (b >= BB) return;
    int s = sin_[b * in_stride + e];
    int d = din_[b * in_stride + e];
    int ns = -1, nd = -1;
    if (s >= 0 && d >= 0) {
        ns = inv[b * NN + s];
        nd = inv[b * NN + d];
    }
    if (ns < 0 || nd < 0) { ns = -1; nd = -1; }
    sout[b * EE + e] = ns;
    dout[b * EE + e] = nd;
}

// ---------------- final MLP per graph ----------------
__global__ __launch_bounds__(256) void mlp_kernel(
    const float* __restrict__ r,
    const float* __restrict__ W1, const float* __restrict__ b1,
    const float* __restrict__ W2, const float* __restrict__ b2,
    const float* __restrict__ W3, const float* __restrict__ b3,
    float* __restrict__ out) {
    __shared__ float sg[256];
    __shared__ float s1[128];
    __shared__ float s2[64];
    int b = blockIdx.x, tid = threadIdx.x;
    sg[tid] = r[b * 256 + tid];
    __syncthreads();
    if (tid < 128) {
        float a = b1[tid];
        for (int j = 0; j < 256; j++) a += sg[j] * W1[tid * 256 + j];
        s1[tid] = fmaxf(a, 0.f);
    }
    __syncthreads();
    if (tid < 64) {
        float a = b2[tid];
        for (int j = 0; j < 128; j++) a += s1[j] * W2[tid * 128 + j];
        s2[tid] = fmaxf(a, 0.f);
    }
    __syncthreads();
    if (tid == 0) {
        float a = b3[0];
        for (int j = 0; j < 64; j++) a += s2[j] * W3[j];
        out[b] = 1.f / (1.f + expf(-a));
    }
}

extern "C" void kernel_launch(void* const* d_in, const int* in_sizes, int n_in,
                              void* d_out, int out_size, void* d_ws, size_t ws_size,
                              hipStream_t stream) {
    const float* x   = (const float*)d_in[0];
    const int*   ei  = (const int*)d_in[1];
    const float* Wr1 = (const float*)d_in[2];
    const float* Wl1 = (const float*)d_in[3];
    const float* b1  = (const float*)d_in[4];
    const float* p1  = (const float*)d_in[5];
    const float* Wr2 = (const float*)d_in[6];
    const float* Wl2 = (const float*)d_in[7];
    const float* b2  = (const float*)d_in[8];
    const float* p2  = (const float*)d_in[9];
    const float* Wr3 = (const float*)d_in[10];
    const float* Wl3 = (const float*)d_in[11];
    const float* b3  = (const float*)d_in[12];
    const float* p3  = (const float*)d_in[13];
    const float* l1W = (const float*)d_in[14];
    const float* l1b = (const float*)d_in[15];
    const float* l2W = (const float*)d_in[16];
    const float* l2b = (const float*)d_in[17];
    const float* l3W = (const float*)d_in[18];
    const float* l3b = (const float*)d_in[19];
    float* out = (float*)d_out;

    char* ws = (char*)d_ws;
    float* bufA = (float*)ws; ws += (size_t)BB * NN * HH * 4;
    float* bufB = (float*)ws; ws += (size_t)BB * NN * HH * 4;
    float* agg  = (float*)ws; ws += (size_t)BB * NN * HH * 4;
    int*   perm = (int*)ws;   ws += (size_t)BB * NN * 4;
    float* vals = (float*)ws; ws += (size_t)BB * NN * 4;
    int*   inv  = (int*)ws;   ws += (size_t)BB * NN * 4;
    int*   curS = (int*)ws;   ws += (size_t)BB * EE * 4;
    int*   curD = (int*)ws;   ws += (size_t)BB * EE * 4;
    float* rbuf = (float*)ws; ws += (size_t)BB * 256 * 4;
    float* part = (float*)ws; ws += (size_t)BB * 16 * 256 * 4;

    hipMemsetAsync(rbuf, 0, BB * 256 * 4, stream);

    // ---------- layer 1 ----------
    hipMemsetAsync(agg, 0, (size_t)BB * NN * FIN * 4, stream);
    hipLaunchKernelGGL(agg1_kernel, dim3(BB * EE * 8 / 256), dim3(256), 0, stream, x, ei, agg);
    hipLaunchKernelGGL(conv1_kernel, dim3(NN / 8, BB), dim3(128), 0, stream, x, agg, Wr1, Wl1, b1, bufA);
    hipLaunchKernelGGL(pool_sort_kernel, dim3(BB), dim3(1024), 0, stream, bufA, p1, NN, KK1, perm, vals, inv);
    {
        int tot = BB * KK1 * 32;
        hipLaunchKernelGGL(gather_kernel, dim3((tot + 255) / 256), dim3(256), 0, stream, bufA, bufB, perm, vals, KK1);
    }
    hipLaunchKernelGGL(readout_part_kernel, dim3(BB * 16), dim3(128), 0, stream, bufB, KK1, part);
    hipLaunchKernelGGL(readout_comb_kernel, dim3(BB), dim3(128), 0, stream, part, rbuf, KK1);
    hipLaunchKernelGGL(remap_kernel, dim3(BB * EE / 256), dim3(256), 0, stream, inv, ei, ei + EE, 2 * EE, curS, curD);

    // ---------- layer 2 ----------
    hipMemsetAsync(agg, 0, (size_t)BB * NN * HH * 4, stream);
    hipLaunchKernelGGL(agg23_kernel, dim3(BB * EE * 32 / 256), dim3(256), 0, stream, bufB, curS, curD, agg);
    hipLaunchKernelGGL(conv23_kernel, dim3((KK1 + 15) / 16, BB), dim3(128), 0, stream, bufB, agg, Wr2, Wl2, b2, bufA, KK1);
    hipLaunchKernelGGL(pool_sort_kernel, dim3(BB), dim3(1024), 0, stream, bufA, p2, KK1, KK2, perm, vals, inv);
    {
        int tot = BB * KK2 * 32;
        hipLaunchKernelGGL(gather_kernel, dim3((tot + 255) / 256), dim3(256), 0, stream, bufA, bufB, perm, vals, KK2);
    }
    hipLaunchKernelGGL(readout_part_kernel, dim3(BB * 16), dim3(128), 0, stream, bufB, KK2, part);
    hipLaunchKernelGGL(readout_comb_kernel, dim3(BB), dim3(128), 0, stream, part, rbuf, KK2);
    hipLaunchKernelGGL(remap_kernel, dim3(BB * EE / 256), dim3(256), 0, stream, inv, curS, curD, EE, curS, curD);

    // ---------- layer 3 ----------
    hipMemsetAsync(agg, 0, (size_t)BB * NN * HH * 4, stream);
    hipLaunchKernelGGL(agg23_kernel, dim3(BB * EE * 32 / 256), dim3(256), 0, stream, bufB, curS, curD, agg);
    hipLaunchKernelGGL(conv23_kernel, dim3((KK2 + 15) / 16, BB), dim3(128), 0, stream, bufB, agg, Wr3, Wl3, b3, bufA, KK2);
    hipLaunchKernelGGL(pool_sort_kernel, dim3(BB), dim3(1024), 0, stream, bufA, p3, KK2, KK3, perm, vals, inv);
    {
        int tot = BB * KK3 * 32;
        hipLaunchKernelGGL(gather_kernel, dim3((tot + 255) / 256), dim3(256), 0, stream, bufA, bufB, perm, vals, KK3);
    }
    hipLaunchKernelGGL(readout_part_kernel, dim3(BB * 16), dim3(128), 0, stream, bufB, KK3, part);
    hipLaunchKernelGGL(readout_comb_kernel, dim3(BB), dim3(128), 0, stream, part, rbuf, KK3);

    // ---------- final MLP ----------
    hipLaunchKernelGGL(mlp_kernel, dim3(BB), dim3(256), 0, stream, rbuf,
                       l1W, l1b, l2W, l2b, l3W, l3b, out);
}

// Round 2
// 744.607 us; speedup vs baseline: 2.2340x; 2.2340x over previous
//
#include <hip/hip_runtime.h>
#include <cstdint>
#include <math.h>

#define BB 16
#define NN 2048
#define EE 32768
#define FIN 32
#define HH 128
#define KK1 1639
#define KK2 1312
#define KK3 1050

// ---------------- CSR build: count incoming edges per dst ----------------
__global__ void csr_count_kernel(const int* __restrict__ dsts, int stride,
                                 int* __restrict__ deg) {
    int t = blockIdx.x * blockDim.x + threadIdx.x;   // B*E
    int e = t & (EE - 1);
    int b = t >> 15;
    if (b >= BB) return;
    int d = dsts[(size_t)b * stride + e];
    if (d >= 0) atomicAdd(&deg[b * NN + d], 1);
}

// ---------------- CSR build: exclusive prefix scan per graph ----------------
__global__ __launch_bounds__(1024) void csr_scan_kernel(
    const int* __restrict__ deg, int* __restrict__ rowptr, int* __restrict__ cursor) {
    __shared__ int sa[NN], sb[NN];
    int b = blockIdx.x, tid = threadIdx.x;
    int* cur = sa; int* nxt = sb;
    for (int i = tid; i < NN; i += 1024) cur[i] = deg[b * NN + i];
    __syncthreads();
    for (int off = 1; off < NN; off <<= 1) {
        for (int i = tid; i < NN; i += 1024) {
            int v = cur[i];
            if (i >= off) v += cur[i - off];
            nxt[i] = v;
        }
        __syncthreads();
        int* t2 = cur; cur = nxt; nxt = t2;
    }
    if (tid == 0) { rowptr[b * (NN + 1)] = 0; cursor[b * (NN + 1)] = 0; }
    for (int i = tid; i < NN; i += 1024) {
        rowptr[b * (NN + 1) + i + 1] = cur[i];
        cursor[b * (NN + 1) + i + 1] = cur[i];
    }
}

// ---------------- CSR build: scatter source ids ----------------
__global__ void csr_fill_kernel(const int* __restrict__ srcs,
                                const int* __restrict__ dsts, int stride,
                                int* __restrict__ cursor, int* __restrict__ csr) {
    int t = blockIdx.x * blockDim.x + threadIdx.x;   // B*E
    int e = t & (EE - 1);
    int b = t >> 15;
    if (b >= BB) return;
    int s = srcs[(size_t)b * stride + e];
    int d = dsts[(size_t)b * stride + e];
    if (s >= 0 && d >= 0) {
        int pos = atomicAdd(&cursor[b * (NN + 1) + d], 1);
        csr[(size_t)b * EE + pos] = s;
    }
}

// ---------------- pull aggregation, F=32 (layer 1) ----------------
__global__ __launch_bounds__(256) void agg1_csr_kernel(
    const float* __restrict__ x, const int* __restrict__ rowptr,
    const int* __restrict__ csr, float* __restrict__ agg) {
    int b = blockIdx.y;
    int g = threadIdx.x >> 5, lane = threadIdx.x & 31;
    int node = blockIdx.x * 8 + g;
    int beg = rowptr[b * (NN + 1) + node];
    int end = rowptr[b * (NN + 1) + node + 1];
    float acc = 0.f;
    for (int j = beg; j < end; j++) {
        int s = csr[(size_t)b * EE + j];
        acc += x[((size_t)b * NN + s) * FIN + lane];
    }
    agg[((size_t)b * NN + node) * FIN + lane] = acc;
}

// ---------------- pull aggregation, F=128 (layers 2/3) ----------------
__global__ __launch_bounds__(128) void agg23_csr_kernel(
    const float* __restrict__ x, const int* __restrict__ rowptr,
    const int* __restrict__ csr, float* __restrict__ agg, int n) {
    int b = blockIdx.y;
    int tid = threadIdx.x;
#pragma unroll
    for (int r = 0; r < 4; r++) {
        int node = blockIdx.x * 4 + r;
        if (node >= n) break;
        int beg = rowptr[b * (NN + 1) + node];
        int end = rowptr[b * (NN + 1) + node + 1];
        float acc = 0.f;
        for (int j = beg; j < end; j++) {
            int s = csr[(size_t)b * EE + j];
            acc += x[((size_t)b * NN + s) * HH + tid];
        }
        agg[((size_t)b * NN + node) * HH + tid] = acc;
    }
}

// ---------------- conv1: h = relu(x@Wr^T + agg@Wl^T + b), F_IN=32 -> H=128 ----------------
__global__ __launch_bounds__(128) void conv1_kernel(
    const float* __restrict__ x, const float* __restrict__ agg,
    const float* __restrict__ Wroot, const float* __restrict__ Wrel,
    const float* __restrict__ bias, float* __restrict__ h) {
    __shared__ float sx[8 * FIN];
    __shared__ float sa[8 * FIN];
    int b = blockIdx.y;
    int r0 = blockIdx.x * 8;
    int tid = threadIdx.x;
    size_t base = ((size_t)b * NN + r0) * FIN;
    for (int idx = tid; idx < 8 * FIN; idx += 128) { sx[idx] = x[base + idx]; sa[idx] = agg[base + idx]; }
    __syncthreads();
    int o = tid;
    float acc[8];
#pragma unroll
    for (int r = 0; r < 8; r++) acc[r] = bias[o];
    for (int j = 0; j < FIN; j += 4) {
        float4 wr = *reinterpret_cast<const float4*>(Wroot + o * FIN + j);
        float4 wl = *reinterpret_cast<const float4*>(Wrel + o * FIN + j);
#pragma unroll
        for (int r = 0; r < 8; r++) {
            float4 xv = *reinterpret_cast<const float4*>(sx + r * FIN + j);
            float4 av = *reinterpret_cast<const float4*>(sa + r * FIN + j);
            acc[r] += xv.x * wr.x + xv.y * wr.y + xv.z * wr.z + xv.w * wr.w
                    + av.x * wl.x + av.y * wl.y + av.z * wl.z + av.w * wl.w;
        }
    }
    size_t ob = ((size_t)b * NN + r0) * HH + o;
#pragma unroll
    for (int r = 0; r < 8; r++) h[ob + (size_t)r * HH] = fmaxf(acc[r], 0.f);
}

// ---------------- conv2/3: H=128 -> H=128, 16 rows per block ----------------
__global__ __launch_bounds__(128) void conv23_kernel(
    const float* __restrict__ x, const float* __restrict__ agg,
    const float* __restrict__ Wroot, const float* __restrict__ Wrel,
    const float* __restrict__ bias, float* __restrict__ h, int n) {
    __shared__ float sx[16 * HH];
    __shared__ float sa[16 * HH];
    int b = blockIdx.y;
    int r0 = blockIdx.x * 16;
    int tid = threadIdx.x;
    size_t base = ((size_t)b * NN + r0) * HH;
    for (int idx = tid; idx < 16 * HH; idx += 128) { sx[idx] = x[base + idx]; sa[idx] = agg[base + idx]; }
    __syncthreads();
    int o = tid;
    float acc[16];
#pragma unroll
    for (int r = 0; r < 16; r++) acc[r] = bias[o];
    for (int j = 0; j < HH; j += 4) {
        float4 wr = *reinterpret_cast<const float4*>(Wroot + o * HH + j);
        float4 wl = *reinterpret_cast<const float4*>(Wrel + o * HH + j);
#pragma unroll
        for (int r = 0; r < 16; r++) {
            float4 xv = *reinterpret_cast<const float4*>(sx + r * HH + j);
            float4 av = *reinterpret_cast<const float4*>(sa + r * HH + j);
            acc[r] += xv.x * wr.x + xv.y * wr.y + xv.z * wr.z + xv.w * wr.w
                    + av.x * wl.x + av.y * wl.y + av.z * wl.z + av.w * wl.w;
        }
    }
#pragma unroll
    for (int r = 0; r < 16; r++) {
        int i = r0 + r;
        if (i < n) h[((size_t)b * NN + i) * HH + o] = fmaxf(acc[r], 0.f);
    }
}

// ---------------- per-graph: scores + full stable descending sort + perm/vals/inv ----------------
__global__ __launch_bounds__(1024) void pool_sort_kernel(
    const float* __restrict__ h, const float* __restrict__ p,
    int n, int k, int* __restrict__ perm, float* __restrict__ vals,
    int* __restrict__ inv) {
    __shared__ unsigned long long keys[NN];
    __shared__ float ssc[NN];
    __shared__ float sp[HH];
    __shared__ float snorm;
    int b = blockIdx.x, tid = threadIdx.x;
    if (tid < HH) sp[tid] = p[tid];
    __syncthreads();
    if (tid == 0) {
        float s = 0.f;
        for (int j = 0; j < HH; j++) s += sp[j] * sp[j];
        snorm = sqrtf(s);
    }
    __syncthreads();
    int wave = tid >> 6, lane = tid & 63;
    for (int i = wave; i < n; i += 16) {
        const float* row = h + ((size_t)b * NN + i) * HH;
        float v = row[lane] * sp[lane] + row[lane + 64] * sp[lane + 64];
#pragma unroll
        for (int off = 32; off; off >>= 1) v += __shfl_xor(v, off);
        if (lane == 0) ssc[i] = tanhf(v / snorm);
    }
    __syncthreads();
    for (int i = tid; i < NN; i += 1024) {
        unsigned long long key;
        if (i < n) {
            unsigned u = __float_as_uint(ssc[i]);
            u = (u & 0x80000000u) ? ~u : (u ^ 0x80000000u);   // monotone ascending
            u = ~u;                                            // -> descending
            key = ((unsigned long long)u << 32) | (unsigned)i; // ties: low index first
        } else {
            key = ~0ULL;
        }
        keys[i] = key;
    }
    __syncthreads();
    // bitonic sort, ascending keys
    for (int kk = 2; kk <= NN; kk <<= 1) {
        for (int j = kk >> 1; j > 0; j >>= 1) {
            for (int i = tid; i < NN; i += 1024) {
                int l = i ^ j;
                if (l > i) {
                    unsigned long long a = keys[i], c = keys[l];
                    bool up = ((i & kk) == 0);
                    if ((a > c) == up) { keys[i] = c; keys[l] = a; }
                }
            }
            __syncthreads();
        }
    }
    for (int i = tid; i < n; i += 1024) inv[b * NN + i] = -1;
    __syncthreads();
    for (int i = tid; i < k; i += 1024) {
        int pi = (int)(keys[i] & 0xFFFFFFFFu);
        perm[b * NN + i] = pi;
        vals[b * NN + i] = ssc[pi];
        inv[b * NN + pi] = i;
    }
}

// ---------------- x_new[i] = h[perm[i]] * vals[i] ----------------
__global__ void gather_kernel(const float* __restrict__ hin,
                              float* __restrict__ xout,
                              const int* __restrict__ perm,
                              const float* __restrict__ vals, int k) {
    int t = blockIdx.x * blockDim.x + threadIdx.x;
    int total = BB * k * 32;
    if (t >= total) return;
    int c = t & 31;
    int rem = t >> 5;
    int i = rem % k;
    int b = rem / k;
    int pi = perm[b * NN + i];
    float v = vals[b * NN + i];
    float4 x4 = *reinterpret_cast<const float4*>(hin + ((size_t)b * NN + pi) * HH + c * 4);
    float4 o4 = make_float4(x4.x * v, x4.y * v, x4.z * v, x4.w * v);
    *reinterpret_cast<float4*>(xout + ((size_t)b * NN + i) * HH + c * 4) = o4;
}

// ---------------- readout: stage 1 partials (16 blocks/graph) ----------------
__global__ __launch_bounds__(128) void readout_part_kernel(
    const float* __restrict__ x, int k, float* __restrict__ part) {
    int b = blockIdx.x >> 4;
    int j = blockIdx.x & 15;
    int f = threadIdx.x;
    float mx = -INFINITY, sm = 0.f;
    for (int i = j; i < k; i += 16) {
        float v = x[((size_t)b * NN + i) * HH + f];
        mx = fmaxf(mx, v);
        sm += v;
    }
    part[(size_t)blockIdx.x * 256 + f] = mx;
    part[(size_t)blockIdx.x * 256 + 128 + f] = sm;
}

// ---------------- readout: combine + accumulate into r ----------------
__global__ __launch_bounds__(128) void readout_comb_kernel(
    const float* __restrict__ part, float* __restrict__ r, int k) {
    int b = blockIdx.x;
    int f = threadIdx.x;
    float mx = -INFINITY, sm = 0.f;
    for (int j = 0; j < 16; j++) {
        mx = fmaxf(mx, part[((size_t)b * 16 + j) * 256 + f]);
        sm += part[((size_t)b * 16 + j) * 256 + 128 + f];
    }
    r[b * 256 + f] += mx;
    r[b * 256 + 128 + f] += sm / (float)k;
}

// ---------------- edge remap through inv; -1 marks invalid ----------------
__global__ void remap_kernel(const int* __restrict__ inv,
                             const int* __restrict__ sin_,
                             const int* __restrict__ din_,
                             int in_stride,
                             int* __restrict__ sout, int* __restrict__ dout) {
    int t = blockIdx.x * blockDim.x + threadIdx.x;   // B*E
    int e = t & (EE - 1);
    int b = t >> 15;
    if (b >= BB) return;
    int s = sin_[(size_t)b * in_stride + e];
    int d = din_[(size_t)b * in_stride + e];
    int ns = -1, nd = -1;
    if (s >= 0 && d >= 0) {
        ns = inv[b * NN + s];
        nd = inv[b * NN + d];
    }
    if (ns < 0 || nd < 0) { ns = -1; nd = -1; }
    sout[b * EE + e] = ns;
    dout[b * EE + e] = nd;
}

// ---------------- final MLP per graph ----------------
__global__ __launch_bounds__(256) void mlp_kernel(
    const float* __restrict__ r,
    const float* __restrict__ W1, const float* __restrict__ b1,
    const float* __restrict__ W2, const float* __restrict__ b2,
    const float* __restrict__ W3, const float* __restrict__ b3,
    float* __restrict__ out) {
    __shared__ float sg[256];
    __shared__ float s1[128];
    __shared__ float s2[64];
    int b = blockIdx.x, tid = threadIdx.x;
    sg[tid] = r[b * 256 + tid];
    __syncthreads();
    if (tid < 128) {
        float a = b1[tid];
        for (int j = 0; j < 256; j++) a += sg[j] * W1[tid * 256 + j];
        s1[tid] = fmaxf(a, 0.f);
    }
    __syncthreads();
    if (tid < 64) {
        float a = b2[tid];
        for (int j = 0; j < 128; j++) a += s1[j] * W2[tid * 128 + j];
        s2[tid] = fmaxf(a, 0.f);
    }
    __syncthreads();
    if (tid == 0) {
        float a = b3[0];
        for (int j = 0; j < 64; j++) a += s2[j] * W3[j];
        out[b] = 1.f / (1.f + expf(-a));
    }
}

extern "C" void kernel_launch(void* const* d_in, const int* in_sizes, int n_in,
                              void* d_out, int out_size, void* d_ws, size_t ws_size,
                              hipStream_t stream) {
    const float* x   = (const float*)d_in[0];
    const int*   ei  = (const int*)d_in[1];
    const float* Wr1 = (const float*)d_in[2];
    const float* Wl1 = (const float*)d_in[3];
    const float* b1  = (const float*)d_in[4];
    const float* p1  = (const float*)d_in[5];
    const float* Wr2 = (const float*)d_in[6];
    const float* Wl2 = (const float*)d_in[7];
    const float* b2  = (const float*)d_in[8];
    const float* p2  = (const float*)d_in[9];
    const float* Wr3 = (const float*)d_in[10];
    const float* Wl3 = (const float*)d_in[11];
    const float* b3  = (const float*)d_in[12];
    const float* p3  = (const float*)d_in[13];
    const float* l1W = (const float*)d_in[14];
    const float* l1b = (const float*)d_in[15];
    const float* l2W = (const float*)d_in[16];
    const float* l2b = (const float*)d_in[17];
    const float* l3W = (const float*)d_in[18];
    const float* l3b = (const float*)d_in[19];
    float* out = (float*)d_out;

    char* ws = (char*)d_ws;
    float* bufA = (float*)ws; ws += (size_t)BB * NN * HH * 4;
    float* bufB = (float*)ws; ws += (size_t)BB * NN * HH * 4;
    float* agg  = (float*)ws; ws += (size_t)BB * NN * HH * 4;
    int*   perm = (int*)ws;   ws += (size_t)BB * NN * 4;
    float* vals = (float*)ws; ws += (size_t)BB * NN * 4;
    int*   inv  = (int*)ws;   ws += (size_t)BB * NN * 4;
    int*   curS = (int*)ws;   ws += (size_t)BB * EE * 4;
    int*   curD = (int*)ws;   ws += (size_t)BB * EE * 4;
    float* rbuf = (float*)ws; ws += (size_t)BB * 256 * 4;
    float* part = (float*)ws; ws += (size_t)BB * 16 * 256 * 4;
    int*   deg  = (int*)ws;   ws += (size_t)BB * NN * 4;
    int*   rowptr = (int*)ws; ws += (size_t)BB * (NN + 1) * 4;
    int*   cursor = (int*)ws; ws += (size_t)BB * (NN + 1) * 4;
    // CSR source array lives in bufA: in every layer, CSR build + aggregation
    // complete BEFORE conv writes bufA, and CSR is dead afterwards.
    int*   csr = (int*)bufA;

    hipMemsetAsync(rbuf, 0, BB * 256 * 4, stream);

    // ---------- layer 1 ----------
    hipMemsetAsync(deg, 0, (size_t)BB * NN * 4, stream);
    hipLaunchKernelGGL(csr_count_kernel, dim3(BB * EE / 256), dim3(256), 0, stream, ei + EE, 2 * EE, deg);
    hipLaunchKernelGGL(csr_scan_kernel, dim3(BB), dim3(1024), 0, stream, deg, rowptr, cursor);
    hipLaunchKernelGGL(csr_fill_kernel, dim3(BB * EE / 256), dim3(256), 0, stream, ei, ei + EE, 2 * EE, cursor, csr);
    hipLaunchKernelGGL(agg1_csr_kernel, dim3(NN / 8, BB), dim3(256), 0, stream, x, rowptr, csr, agg);
    hipLaunchKernelGGL(conv1_kernel, dim3(NN / 8, BB), dim3(128), 0, stream, x, agg, Wr1, Wl1, b1, bufA);
    hipLaunchKernelGGL(pool_sort_kernel, dim3(BB), dim3(1024), 0, stream, bufA, p1, NN, KK1, perm, vals, inv);
    {
        int tot = BB * KK1 * 32;
        hipLaunchKernelGGL(gather_kernel, dim3((tot + 255) / 256), dim3(256), 0, stream, bufA, bufB, perm, vals, KK1);
    }
    hipLaunchKernelGGL(readout_part_kernel, dim3(BB * 16), dim3(128), 0, stream, bufB, KK1, part);
    hipLaunchKernelGGL(readout_comb_kernel, dim3(BB), dim3(128), 0, stream, part, rbuf, KK1);
    hipLaunchKernelGGL(remap_kernel, dim3(BB * EE / 256), dim3(256), 0, stream, inv, ei, ei + EE, 2 * EE, curS, curD);

    // ---------- layer 2 ----------
    hipMemsetAsync(deg, 0, (size_t)BB * NN * 4, stream);
    hipLaunchKernelGGL(csr_count_kernel, dim3(BB * EE / 256), dim3(256), 0, stream, curD, EE, deg);
    hipLaunchKernelGGL(csr_scan_kernel, dim3(BB), dim3(1024), 0, stream, deg, rowptr, cursor);
    hipLaunchKernelGGL(csr_fill_kernel, dim3(BB * EE / 256), dim3(256), 0, stream, curS, curD, EE, cursor, csr);
    hipLaunchKernelGGL(agg23_csr_kernel, dim3((KK1 + 3) / 4, BB), dim3(128), 0, stream, bufB, rowptr, csr, agg, KK1);
    hipLaunchKernelGGL(conv23_kernel, dim3((KK1 + 15) / 16, BB), dim3(128), 0, stream, bufB, agg, Wr2, Wl2, b2, bufA, KK1);
    hipLaunchKernelGGL(pool_sort_kernel, dim3(BB), dim3(1024), 0, stream, bufA, p2, KK1, KK2, perm, vals, inv);
    {
        int tot = BB * KK2 * 32;
        hipLaunchKernelGGL(gather_kernel, dim3((tot + 255) / 256), dim3(256), 0, stream, bufA, bufB, perm, vals, KK2);
    }
    hipLaunchKernelGGL(readout_part_kernel, dim3(BB * 16), dim3(128), 0, stream, bufB, KK2, part);
    hipLaunchKernelGGL(readout_comb_kernel, dim3(BB), dim3(128), 0, stream, part, rbuf, KK2);
    hipLaunchKernelGGL(remap_kernel, dim3(BB * EE / 256), dim3(256), 0, stream, inv, curS, curD, EE, curS, curD);

    // ---------- layer 3 ----------
    hipMemsetAsync(deg, 0, (size_t)BB * NN * 4, stream);
    hipLaunchKernelGGL(csr_count_kernel, dim3(BB * EE / 256), dim3(256), 0, stream, curD, EE, deg);
    hipLaunchKernelGGL(csr_scan_kernel, dim3(BB), dim3(1024), 0, stream, deg, rowptr, cursor);
    hipLaunchKernelGGL(csr_fill_kernel, dim3(BB * EE / 256), dim3(256), 0, stream, curS, curD, EE, cursor, csr);
    hipLaunchKernelGGL(agg23_csr_kernel, dim3((KK2 + 3) / 4, BB), dim3(128), 0, stream, bufB, rowptr, csr, agg, KK2);
    hipLaunchKernelGGL(conv23_kernel, dim3((KK2 + 15) / 16, BB), dim3(128), 0, stream, bufB, agg, Wr3, Wl3, b3, bufA, KK2);
    hipLaunchKernelGGL(pool_sort_kernel, dim3(BB), dim3(1024), 0, stream, bufA, p3, KK2, KK3, perm, vals, inv);
    {
        int tot = BB * KK3 * 32;
        hipLaunchKernelGGL(gather_kernel, dim3((tot + 255) / 256), dim3(256), 0, stream, bufA, bufB, perm, vals, KK3);
    }
    hipLaunchKernelGGL(readout_part_kernel, dim3(BB * 16), dim3(128), 0, stream, bufB, KK3, part);
    hipLaunchKernelGGL(readout_comb_kernel, dim3(BB), dim3(128), 0, stream, part, rbuf, KK3);

    // ---------- final MLP ----------
    hipLaunchKernelGGL(mlp_kernel, dim3(BB), dim3(256), 0, stream, rbuf,
                       l1W, l1b, l2W, l2b, l3W, l3b, out);
}

// Round 3
// 580.395 us; speedup vs baseline: 2.8660x; 1.2829x over previous
//
#include <hip/hip_runtime.h>
#include <cstdint>
#include <math.h>

#define BB 16
#define NN 2048
#define EE 32768
#define FIN 32
#define HH 128
#define KK1 1639
#define KK2 1312
#define KK3 1050

// ---------------- CSR build: count incoming edges per dst ----------------
__global__ void csr_count_kernel(const int* __restrict__ dsts, int stride,
                                 int* __restrict__ deg) {
    int t = blockIdx.x * blockDim.x + threadIdx.x;   // B*E
    int e = t & (EE - 1);
    int b = t >> 15;
    if (b >= BB) return;
    int d = dsts[(size_t)b * stride + e];
    if (d >= 0) atomicAdd(&deg[b * NN + d], 1);
}

// ---------------- CSR build: exclusive prefix scan per graph ----------------
__global__ __launch_bounds__(1024) void csr_scan_kernel(
    const int* __restrict__ deg, int* __restrict__ rowptr, int* __restrict__ cursor) {
    __shared__ int sa[NN], sb[NN];
    int b = blockIdx.x, tid = threadIdx.x;
    int* cur = sa; int* nxt = sb;
    for (int i = tid; i < NN; i += 1024) cur[i] = deg[b * NN + i];
    __syncthreads();
    for (int off = 1; off < NN; off <<= 1) {
        for (int i = tid; i < NN; i += 1024) {
            int v = cur[i];
            if (i >= off) v += cur[i - off];
            nxt[i] = v;
        }
        __syncthreads();
        int* t2 = cur; cur = nxt; nxt = t2;
    }
    if (tid == 0) { rowptr[b * (NN + 1)] = 0; cursor[b * (NN + 1)] = 0; }
    for (int i = tid; i < NN; i += 1024) {
        rowptr[b * (NN + 1) + i + 1] = cur[i];
        cursor[b * (NN + 1) + i + 1] = cur[i];
    }
}

// ---------------- CSR build: scatter source ids ----------------
__global__ void csr_fill_kernel(const int* __restrict__ srcs,
                                const int* __restrict__ dsts, int stride,
                                int* __restrict__ cursor, int* __restrict__ csr) {
    int t = blockIdx.x * blockDim.x + threadIdx.x;   // B*E
    int e = t & (EE - 1);
    int b = t >> 15;
    if (b >= BB) return;
    int s = srcs[(size_t)b * stride + e];
    int d = dsts[(size_t)b * stride + e];
    if (s >= 0 && d >= 0) {
        int pos = atomicAdd(&cursor[b * (NN + 1) + d], 1);
        csr[(size_t)b * EE + pos] = s;
    }
}

// ---------------- pull aggregation, F=32 (layer 1) ----------------
__global__ __launch_bounds__(256) void agg1_csr_kernel(
    const float* __restrict__ x, const int* __restrict__ rowptr,
    const int* __restrict__ csr, float* __restrict__ agg) {
    int b = blockIdx.y;
    int g = threadIdx.x >> 5, lane = threadIdx.x & 31;
    int node = blockIdx.x * 8 + g;
    int beg = rowptr[b * (NN + 1) + node];
    int end = rowptr[b * (NN + 1) + node + 1];
    float acc = 0.f;
    for (int j = beg; j < end; j++) {
        int s = csr[(size_t)b * EE + j];
        acc += x[((size_t)b * NN + s) * FIN + lane];
    }
    agg[((size_t)b * NN + node) * FIN + lane] = acc;
}

// ---------------- pull aggregation, F=128 (layers 2/3) ----------------
__global__ __launch_bounds__(128) void agg23_csr_kernel(
    const float* __restrict__ x, const int* __restrict__ rowptr,
    const int* __restrict__ csr, float* __restrict__ agg, int n) {
    int b = blockIdx.y;
    int tid = threadIdx.x;
#pragma unroll
    for (int r = 0; r < 4; r++) {
        int node = blockIdx.x * 4 + r;
        if (node >= n) break;
        int beg = rowptr[b * (NN + 1) + node];
        int end = rowptr[b * (NN + 1) + node + 1];
        float acc = 0.f;
        for (int j = beg; j < end; j++) {
            int s = csr[(size_t)b * EE + j];
            acc += x[((size_t)b * NN + s) * HH + tid];
        }
        agg[((size_t)b * NN + node) * HH + tid] = acc;
    }
}

// ---------------- conv1: h = relu(x@Wr^T + agg@Wl^T + b), F_IN=32 -> H=128 ----------------
__global__ __launch_bounds__(128) void conv1_kernel(
    const float* __restrict__ x, const float* __restrict__ agg,
    const float* __restrict__ Wroot, const float* __restrict__ Wrel,
    const float* __restrict__ bias, float* __restrict__ h) {
    __shared__ float sx[8 * FIN];
    __shared__ float sa[8 * FIN];
    int b = blockIdx.y;
    int r0 = blockIdx.x * 8;
    int tid = threadIdx.x;
    size_t base = ((size_t)b * NN + r0) * FIN;
    for (int idx = tid; idx < 8 * FIN; idx += 128) { sx[idx] = x[base + idx]; sa[idx] = agg[base + idx]; }
    __syncthreads();
    int o = tid;
    float acc[8];
#pragma unroll
    for (int r = 0; r < 8; r++) acc[r] = bias[o];
    for (int j = 0; j < FIN; j += 4) {
        float4 wr = *reinterpret_cast<const float4*>(Wroot + o * FIN + j);
        float4 wl = *reinterpret_cast<const float4*>(Wrel + o * FIN + j);
#pragma unroll
        for (int r = 0; r < 8; r++) {
            float4 xv = *reinterpret_cast<const float4*>(sx + r * FIN + j);
            float4 av = *reinterpret_cast<const float4*>(sa + r * FIN + j);
            acc[r] += xv.x * wr.x + xv.y * wr.y + xv.z * wr.z + xv.w * wr.w
                    + av.x * wl.x + av.y * wl.y + av.z * wl.z + av.w * wl.w;
        }
    }
    size_t ob = ((size_t)b * NN + r0) * HH + o;
#pragma unroll
    for (int r = 0; r < 8; r++) h[ob + (size_t)r * HH] = fmaxf(acc[r], 0.f);
}

// ---------------- conv2/3: H=128 -> H=128, 16 rows per block ----------------
__global__ __launch_bounds__(128) void conv23_kernel(
    const float* __restrict__ x, const float* __restrict__ agg,
    const float* __restrict__ Wroot, const float* __restrict__ Wrel,
    const float* __restrict__ bias, float* __restrict__ h, int n) {
    __shared__ float sx[16 * HH];
    __shared__ float sa[16 * HH];
    int b = blockIdx.y;
    int r0 = blockIdx.x * 16;
    int tid = threadIdx.x;
    size_t base = ((size_t)b * NN + r0) * HH;
    for (int idx = tid; idx < 16 * HH; idx += 128) { sx[idx] = x[base + idx]; sa[idx] = agg[base + idx]; }
    __syncthreads();
    int o = tid;
    float acc[16];
#pragma unroll
    for (int r = 0; r < 16; r++) acc[r] = bias[o];
    for (int j = 0; j < HH; j += 4) {
        float4 wr = *reinterpret_cast<const float4*>(Wroot + o * HH + j);
        float4 wl = *reinterpret_cast<const float4*>(Wrel + o * HH + j);
#pragma unroll
        for (int r = 0; r < 16; r++) {
            float4 xv = *reinterpret_cast<const float4*>(sx + r * HH + j);
            float4 av = *reinterpret_cast<const float4*>(sa + r * HH + j);
            acc[r] += xv.x * wr.x + xv.y * wr.y + xv.z * wr.z + xv.w * wr.w
                    + av.x * wl.x + av.y * wl.y + av.z * wl.z + av.w * wl.w;
        }
    }
#pragma unroll
    for (int r = 0; r < 16; r++) {
        int i = r0 + r;
        if (i < n) h[((size_t)b * NN + i) * HH + o] = fmaxf(acc[r], 0.f);
    }
}

// ---------------- scores + sortable keys, one wave per row ----------------
__global__ __launch_bounds__(256) void score_kernel(
    const float* __restrict__ h, const float* __restrict__ p, int n,
    unsigned long long* __restrict__ keys, float* __restrict__ ssc) {
    int b = blockIdx.y;
    int row = blockIdx.x * 4 + (threadIdx.x >> 6);
    int lane = threadIdx.x & 63;
    unsigned long long key = ~0ULL;
    float sc = 0.f;
    if (row < n) {
        const float* r = h + ((size_t)b * NN + row) * HH;
        float p0 = p[lane], p1 = p[lane + 64];
        float ps = p0 * p0 + p1 * p1;
        float v = r[lane] * p0 + r[lane + 64] * p1;
#pragma unroll
        for (int off = 32; off; off >>= 1) {
            v += __shfl_xor(v, off);
            ps += __shfl_xor(ps, off);
        }
        sc = tanhf(v / sqrtf(ps));
        unsigned u = __float_as_uint(sc);
        u = (u & 0x80000000u) ? ~u : (u ^ 0x80000000u);   // monotone ascending
        u = ~u;                                            // -> descending
        key = ((unsigned long long)u << 32) | (unsigned)row;
    }
    if (lane == 0) { keys[b * NN + row] = key; ssc[b * NN + row] = sc; }
}

// ---------------- exact rank via all-pairs compare (keys unique) ----------------
__global__ __launch_bounds__(256) void rank_kernel(
    const unsigned long long* __restrict__ keys, const float* __restrict__ ssc,
    int n, int k, int* __restrict__ perm, float* __restrict__ vals,
    int* __restrict__ inv) {
    __shared__ unsigned long long sk[NN];
    int b = blockIdx.y;
    for (int i = threadIdx.x; i < NN; i += 256) sk[i] = keys[(size_t)b * NN + i];
    __syncthreads();
    int i = blockIdx.x * 256 + threadIdx.x;
    unsigned long long my = sk[i];
    int rank = 0;
#pragma unroll 8
    for (int j = 0; j < NN; j++) rank += (sk[j] < my) ? 1 : 0;
    if (i < n) {
        if (rank < k) {
            perm[b * NN + rank] = i;
            vals[b * NN + rank] = ssc[(size_t)b * NN + i];
            inv[b * NN + i] = rank;
        } else {
            inv[b * NN + i] = -1;
        }
    }
}

// ---------------- x_new[i] = h[perm[i]] * vals[i] ----------------
__global__ void gather_kernel(const float* __restrict__ hin,
                              float* __restrict__ xout,
                              const int* __restrict__ perm,
                              const float* __restrict__ vals, int k) {
    int t = blockIdx.x * blockDim.x + threadIdx.x;
    int total = BB * k * 32;
    if (t >= total) return;
    int c = t & 31;
    int rem = t >> 5;
    int i = rem % k;
    int b = rem / k;
    int pi = perm[b * NN + i];
    float v = vals[b * NN + i];
    float4 x4 = *reinterpret_cast<const float4*>(hin + ((size_t)b * NN + pi) * HH + c * 4);
    float4 o4 = make_float4(x4.x * v, x4.y * v, x4.z * v, x4.w * v);
    *reinterpret_cast<float4*>(xout + ((size_t)b * NN + i) * HH + c * 4) = o4;
}

// ---------------- readout: stage 1 partials (16 blocks/graph) ----------------
__global__ __launch_bounds__(128) void readout_part_kernel(
    const float* __restrict__ x, int k, float* __restrict__ part) {
    int b = blockIdx.x >> 4;
    int j = blockIdx.x & 15;
    int f = threadIdx.x;
    float mx = -INFINITY, sm = 0.f;
    for (int i = j; i < k; i += 16) {
        float v = x[((size_t)b * NN + i) * HH + f];
        mx = fmaxf(mx, v);
        sm += v;
    }
    part[(size_t)blockIdx.x * 256 + f] = mx;
    part[(size_t)blockIdx.x * 256 + 128 + f] = sm;
}

// ---------------- readout: combine + accumulate into r ----------------
__global__ __launch_bounds__(128) void readout_comb_kernel(
    const float* __restrict__ part, float* __restrict__ r, int k) {
    int b = blockIdx.x;
    int f = threadIdx.x;
    float mx = -INFINITY, sm = 0.f;
    for (int j = 0; j < 16; j++) {
        mx = fmaxf(mx, part[((size_t)b * 16 + j) * 256 + f]);
        sm += part[((size_t)b * 16 + j) * 256 + 128 + f];
    }
    r[b * 256 + f] += mx;
    r[b * 256 + 128 + f] += sm / (float)k;
}

// ---------------- edge remap through inv; -1 marks invalid ----------------
__global__ void remap_kernel(const int* __restrict__ inv,
                             const int* __restrict__ sin_,
                             const int* __restrict__ din_,
                             int in_stride,
                             int* __restrict__ sout, int* __restrict__ dout) {
    int t = blockIdx.x * blockDim.x + threadIdx.x;   // B*E
    int e = t & (EE - 1);
    int b = t >> 15;
    if (b >= BB) return;
    int s = sin_[(size_t)b * in_stride + e];
    int d = din_[(size_t)b * in_stride + e];
    int ns = -1, nd = -1;
    if (s >= 0 && d >= 0) {
        ns = inv[b * NN + s];
        nd = inv[b * NN + d];
    }
    if (ns < 0 || nd < 0) { ns = -1; nd = -1; }
    sout[b * EE + e] = ns;
    dout[b * EE + e] = nd;
}

// ---------------- final MLP per graph ----------------
__global__ __launch_bounds__(256) void mlp_kernel(
    const float* __restrict__ r,
    const float* __restrict__ W1, const float* __restrict__ b1,
    const float* __restrict__ W2, const float* __restrict__ b2,
    const float* __restrict__ W3, const float* __restrict__ b3,
    float* __restrict__ out) {
    __shared__ float sg[256];
    __shared__ float s1[128];
    __shared__ float s2[64];
    int b = blockIdx.x, tid = threadIdx.x;
    sg[tid] = r[b * 256 + tid];
    __syncthreads();
    if (tid < 128) {
        float a = b1[tid];
        for (int j = 0; j < 256; j++) a += sg[j] * W1[tid * 256 + j];
        s1[tid] = fmaxf(a, 0.f);
    }
    __syncthreads();
    if (tid < 64) {
        float a = b2[tid];
        for (int j = 0; j < 128; j++) a += s1[j] * W2[tid * 128 + j];
        s2[tid] = fmaxf(a, 0.f);
    }
    __syncthreads();
    if (tid == 0) {
        float a = b3[0];
        for (int j = 0; j < 64; j++) a += s2[j] * W3[j];
        out[b] = 1.f / (1.f + expf(-a));
    }
}

extern "C" void kernel_launch(void* const* d_in, const int* in_sizes, int n_in,
                              void* d_out, int out_size, void* d_ws, size_t ws_size,
                              hipStream_t stream) {
    const float* x   = (const float*)d_in[0];
    const int*   ei  = (const int*)d_in[1];
    const float* Wr1 = (const float*)d_in[2];
    const float* Wl1 = (const float*)d_in[3];
    const float* b1  = (const float*)d_in[4];
    const float* p1  = (const float*)d_in[5];
    const float* Wr2 = (const float*)d_in[6];
    const float* Wl2 = (const float*)d_in[7];
    const float* b2  = (const float*)d_in[8];
    const float* p2  = (const float*)d_in[9];
    const float* Wr3 = (const float*)d_in[10];
    const float* Wl3 = (const float*)d_in[11];
    const float* b3  = (const float*)d_in[12];
    const float* p3  = (const float*)d_in[13];
    const float* l1W = (const float*)d_in[14];
    const float* l1b = (const float*)d_in[15];
    const float* l2W = (const float*)d_in[16];
    const float* l2b = (const float*)d_in[17];
    const float* l3W = (const float*)d_in[18];
    const float* l3b = (const float*)d_in[19];
    float* out = (float*)d_out;

    char* ws = (char*)d_ws;
    float* bufA = (float*)ws; ws += (size_t)BB * NN * HH * 4;
    float* bufB = (float*)ws; ws += (size_t)BB * NN * HH * 4;
    float* agg  = (float*)ws; ws += (size_t)BB * NN * HH * 4;
    int*   perm = (int*)ws;   ws += (size_t)BB * NN * 4;
    float* vals = (float*)ws; ws += (size_t)BB * NN * 4;
    int*   inv  = (int*)ws;   ws += (size_t)BB * NN * 4;
    int*   curS = (int*)ws;   ws += (size_t)BB * EE * 4;
    int*   curD = (int*)ws;   ws += (size_t)BB * EE * 4;
    float* rbuf = (float*)ws; ws += (size_t)BB * 256 * 4;
    float* part = (float*)ws; ws += (size_t)BB * 16 * 256 * 4;
    int*   deg  = (int*)ws;   ws += (size_t)BB * NN * 4;
    int*   rowptr = (int*)ws; ws += (size_t)BB * (NN + 1) * 4;
    int*   cursor = (int*)ws; ws += (size_t)BB * (NN + 1) * 4;
    unsigned long long* keys = (unsigned long long*)ws; ws += (size_t)BB * NN * 8;
    float* ssc  = (float*)ws; ws += (size_t)BB * NN * 4;
    // CSR source array lives in bufA: in every layer, CSR build + aggregation
    // complete BEFORE conv writes bufA, and CSR is dead afterwards.
    int*   csr = (int*)bufA;

    hipMemsetAsync(rbuf, 0, BB * 256 * 4, stream);

    // ---------- layer 1 ----------
    hipMemsetAsync(deg, 0, (size_t)BB * NN * 4, stream);
    hipLaunchKernelGGL(csr_count_kernel, dim3(BB * EE / 256), dim3(256), 0, stream, ei + EE, 2 * EE, deg);
    hipLaunchKernelGGL(csr_scan_kernel, dim3(BB), dim3(1024), 0, stream, deg, rowptr, cursor);
    hipLaunchKernelGGL(csr_fill_kernel, dim3(BB * EE / 256), dim3(256), 0, stream, ei, ei + EE, 2 * EE, cursor, csr);
    hipLaunchKernelGGL(agg1_csr_kernel, dim3(NN / 8, BB), dim3(256), 0, stream, x, rowptr, csr, agg);
    hipLaunchKernelGGL(conv1_kernel, dim3(NN / 8, BB), dim3(128), 0, stream, x, agg, Wr1, Wl1, b1, bufA);
    hipLaunchKernelGGL(score_kernel, dim3(NN / 4, BB), dim3(256), 0, stream, bufA, p1, NN, keys, ssc);
    hipLaunchKernelGGL(rank_kernel, dim3(NN / 256, BB), dim3(256), 0, stream, keys, ssc, NN, KK1, perm, vals, inv);
    {
        int tot = BB * KK1 * 32;
        hipLaunchKernelGGL(gather_kernel, dim3((tot + 255) / 256), dim3(256), 0, stream, bufA, bufB, perm, vals, KK1);
    }
    hipLaunchKernelGGL(readout_part_kernel, dim3(BB * 16), dim3(128), 0, stream, bufB, KK1, part);
    hipLaunchKernelGGL(readout_comb_kernel, dim3(BB), dim3(128), 0, stream, part, rbuf, KK1);
    hipLaunchKernelGGL(remap_kernel, dim3(BB * EE / 256), dim3(256), 0, stream, inv, ei, ei + EE, 2 * EE, curS, curD);

    // ---------- layer 2 ----------
    hipMemsetAsync(deg, 0, (size_t)BB * NN * 4, stream);
    hipLaunchKernelGGL(csr_count_kernel, dim3(BB * EE / 256), dim3(256), 0, stream, curD, EE, deg);
    hipLaunchKernelGGL(csr_scan_kernel, dim3(BB), dim3(1024), 0, stream, deg, rowptr, cursor);
    hipLaunchKernelGGL(csr_fill_kernel, dim3(BB * EE / 256), dim3(256), 0, stream, curS, curD, EE, cursor, csr);
    hipLaunchKernelGGL(agg23_csr_kernel, dim3((KK1 + 3) / 4, BB), dim3(128), 0, stream, bufB, rowptr, csr, agg, KK1);
    hipLaunchKernelGGL(conv23_kernel, dim3((KK1 + 15) / 16, BB), dim3(128), 0, stream, bufB, agg, Wr2, Wl2, b2, bufA, KK1);
    hipLaunchKernelGGL(score_kernel, dim3(NN / 4, BB), dim3(256), 0, stream, bufA, p2, KK1, keys, ssc);
    hipLaunchKernelGGL(rank_kernel, dim3(NN / 256, BB), dim3(256), 0, stream, keys, ssc, KK1, KK2, perm, vals, inv);
    {
        int tot = BB * KK2 * 32;
        hipLaunchKernelGGL(gather_kernel, dim3((tot + 255) / 256), dim3(256), 0, stream, bufA, bufB, perm, vals, KK2);
    }
    hipLaunchKernelGGL(readout_part_kernel, dim3(BB * 16), dim3(128), 0, stream, bufB, KK2, part);
    hipLaunchKernelGGL(readout_comb_kernel, dim3(BB), dim3(128), 0, stream, part, rbuf, KK2);
    hipLaunchKernelGGL(remap_kernel, dim3(BB * EE / 256), dim3(256), 0, stream, inv, curS, curD, EE, curS, curD);

    // ---------- layer 3 ----------
    hipMemsetAsync(deg, 0, (size_t)BB * NN * 4, stream);
    hipLaunchKernelGGL(csr_count_kernel, dim3(BB * EE / 256), dim3(256), 0, stream, curD, EE, deg);
    hipLaunchKernelGGL(csr_scan_kernel, dim3(BB), dim3(1024), 0, stream, deg, rowptr, cursor);
    hipLaunchKernelGGL(csr_fill_kernel, dim3(BB * EE / 256), dim3(256), 0, stream, curS, curD, EE, cursor, csr);
    hipLaunchKernelGGL(agg23_csr_kernel, dim3((KK2 + 3) / 4, BB), dim3(128), 0, stream, bufB, rowptr, csr, agg, KK2);
    hipLaunchKernelGGL(conv23_kernel, dim3((KK2 + 15) / 16, BB), dim3(128), 0, stream, bufB, agg, Wr3, Wl3, b3, bufA, KK2);
    hipLaunchKernelGGL(score_kernel, dim3(NN / 4, BB), dim3(256), 0, stream, bufA, p3, KK2, keys, ssc);
    hipLaunchKernelGGL(rank_kernel, dim3(NN / 256, BB), dim3(256), 0, stream, keys, ssc, KK2, KK3, perm, vals, inv);
    {
        int tot = BB * KK3 * 32;
        hipLaunchKernelGGL(gather_kernel, dim3((tot + 255) / 256), dim3(256), 0, stream, bufA, bufB, perm, vals, KK3);
    }
    hipLaunchKernelGGL(readout_part_kernel, dim3(BB * 16), dim3(128), 0, stream, bufB, KK3, part);
    hipLaunchKernelGGL(readout_comb_kernel, dim3(BB), dim3(128), 0, stream, part, rbuf, KK3);

    // ---------- final MLP ----------
    hipLaunchKernelGGL(mlp_kernel, dim3(BB), dim3(256), 0, stream, rbuf,
                       l1W, l1b, l2W, l2b, l3W, l3b, out);
}

// Round 4
// 537.503 us; speedup vs baseline: 3.0947x; 1.0798x over previous
//
#include <hip/hip_runtime.h>
#include <cstdint>
#include <math.h>

#define BB 16
#define NN 2048
#define EE 32768
#define FIN 32
#define HH 128
#define KK1 1639
#define KK2 1312
#define KK3 1050

// ---------------- CSR build: count incoming edges per dst ----------------
__global__ void csr_count_kernel(const int* __restrict__ dsts, int stride,
                                 int* __restrict__ deg) {
    int t = blockIdx.x * blockDim.x + threadIdx.x;   // B*E
    int e = t & (EE - 1);
    int b = t >> 15;
    if (b >= BB) return;
    int d = dsts[(size_t)b * stride + e];
    if (d >= 0) atomicAdd(&deg[b * NN + d], 1);
}

// ---------------- CSR build: exclusive prefix scan per graph (shfl-based) ----------------
__global__ __launch_bounds__(1024) void csr_scan_kernel(
    const int* __restrict__ deg, int* __restrict__ rowptr, int* __restrict__ cursor) {
    __shared__ int wsum[16];
    int b = blockIdx.x, t = threadIdx.x;
    int d0 = deg[b * NN + 2 * t];
    int d1 = deg[b * NN + 2 * t + 1];
    int s = d0 + d1;
    int lane = t & 63;
    int v = s;
#pragma unroll
    for (int off = 1; off < 64; off <<= 1) {
        int u = __shfl_up(v, off);
        if (lane >= off) v += u;
    }
    if (lane == 63) wsum[t >> 6] = v;
    __syncthreads();
    int w = t >> 6;
    int woff = 0;
#pragma unroll
    for (int i = 0; i < 16; i++) woff += (i < w) ? wsum[i] : 0;
    int excl = woff + v - s;                 // exclusive prefix of this thread's pair
    int base = b * (NN + 1);
    if (t == 0) { rowptr[base] = 0; cursor[base] = 0; }
    int p0 = excl + d0, p1 = excl + d0 + d1;
    rowptr[base + 2 * t + 1] = p0; cursor[base + 2 * t + 1] = p0;
    rowptr[base + 2 * t + 2] = p1; cursor[base + 2 * t + 2] = p1;
}

// ---------------- CSR build: scatter source ids ----------------
__global__ void csr_fill_kernel(const int* __restrict__ srcs,
                                const int* __restrict__ dsts, int stride,
                                int* __restrict__ cursor, int* __restrict__ csr) {
    int t = blockIdx.x * blockDim.x + threadIdx.x;   // B*E
    int e = t & (EE - 1);
    int b = t >> 15;
    if (b >= BB) return;
    int s = srcs[(size_t)b * stride + e];
    int d = dsts[(size_t)b * stride + e];
    if (s >= 0 && d >= 0) {
        int pos = atomicAdd(&cursor[b * (NN + 1) + d], 1);
        csr[(size_t)b * EE + pos] = s;
    }
}

// ---------------- pull aggregation, F=32 (layer 1) ----------------
__global__ __launch_bounds__(256) void agg1_csr_kernel(
    const float* __restrict__ x, const int* __restrict__ rowptr,
    const int* __restrict__ csr, float* __restrict__ agg) {
    int b = blockIdx.y;
    int g = threadIdx.x >> 5, lane = threadIdx.x & 31;
    int node = blockIdx.x * 8 + g;
    int beg = rowptr[b * (NN + 1) + node];
    int end = rowptr[b * (NN + 1) + node + 1];
    float acc = 0.f;
    for (int j = beg; j < end; j++) {
        int s = csr[(size_t)b * EE + j];
        acc += x[((size_t)b * NN + s) * FIN + lane];
    }
    agg[((size_t)b * NN + node) * FIN + lane] = acc;
}

// ---------------- pull aggregation, F=128 (layers 2/3) ----------------
__global__ __launch_bounds__(128) void agg23_csr_kernel(
    const float* __restrict__ x, const int* __restrict__ rowptr,
    const int* __restrict__ csr, float* __restrict__ agg, int n) {
    int b = blockIdx.y;
    int tid = threadIdx.x;
#pragma unroll
    for (int r = 0; r < 4; r++) {
        int node = blockIdx.x * 4 + r;
        if (node >= n) break;
        int beg = rowptr[b * (NN + 1) + node];
        int end = rowptr[b * (NN + 1) + node + 1];
        float acc = 0.f;
        for (int j = beg; j < end; j++) {
            int s = csr[(size_t)b * EE + j];
            acc += x[((size_t)b * NN + s) * HH + tid];
        }
        agg[((size_t)b * NN + node) * HH + tid] = acc;
    }
}

// ---------------- fused conv + score/key: h = relu([x|agg] @ [Wr|Wl]^T + b) ----------------
// 64 rows x 128 cols per block; 256 threads, each an 8x4 register tile.
// LDS tiles stored TRANSPOSED (j-major) so inner loop = 3 ds_read_b128 + 32 FMA.
// Epilogue computes TopK score = tanh(h.p/||p||) via 32-lane shfl reduce.
template<int FI>
__global__ __launch_bounds__(256) void conv_fused_kernel(
    const float* __restrict__ x, const float* __restrict__ agg,
    const float* __restrict__ Wroot, const float* __restrict__ Wrel,
    const float* __restrict__ bias, const float* __restrict__ p,
    float* __restrict__ h, unsigned long long* __restrict__ keys,
    float* __restrict__ ssc, int n) {
    constexpr int NCH = (2 * FI) / 64;      // K-chunks of 64
    __shared__ float sxt[64][65];           // [j][row]
    __shared__ float swt[64][129];          // [j][col]
    __shared__ float sp[HH];
    __shared__ float snorm;

    int b = blockIdx.y;
    int r0 = blockIdx.x * 64;
    int t = threadIdx.x;

    if (t < HH) sp[t] = p[t];
    __syncthreads();
    if (t < 64) {
        float v = sp[t] * sp[t] + sp[t + 64] * sp[t + 64];
#pragma unroll
        for (int off = 32; off; off >>= 1) v += __shfl_xor(v, off);
        if (t == 0) snorm = sqrtf(v);
    }

    int cg = t & 31;          // col group (4 cols)
    int rg = t >> 5;          // row group (8 rows)
    int c4 = cg * 4;
    int rl = rg * 8;

    float acc[8][4];
#pragma unroll
    for (int i = 0; i < 8; i++)
#pragma unroll
        for (int j = 0; j < 4; j++) acc[i][j] = 0.f;

    for (int ch = 0; ch < NCH; ch++) {
        int j0 = ch * 64;
        __syncthreads();
        // stage x/agg tile (64 rows x 64 j), transposed into sxt
#pragma unroll
        for (int it = 0; it < 4; it++) {
            int idx = t + it * 256;
            int row = idx >> 4;
            int j4 = idx & 15;
            int jj = j0 + j4 * 4;
            const float* src = (jj < FI)
                ? (x + ((size_t)b * NN + r0 + row) * FI + jj)
                : (agg + ((size_t)b * NN + r0 + row) * FI + (jj - FI));
            float4 v = *reinterpret_cast<const float4*>(src);
            sxt[j4 * 4 + 0][row] = v.x;
            sxt[j4 * 4 + 1][row] = v.y;
            sxt[j4 * 4 + 2][row] = v.z;
            sxt[j4 * 4 + 3][row] = v.w;
        }
        // stage W tile (128 cols x 64 j), transposed into swt
#pragma unroll
        for (int it = 0; it < 8; it++) {
            int idx = t + it * 256;
            int c = idx >> 4;
            int j4 = idx & 15;
            int jj = j0 + j4 * 4;
            const float* src = (jj < FI)
                ? (Wroot + (size_t)c * FI + jj)
                : (Wrel + (size_t)c * FI + (jj - FI));
            float4 v = *reinterpret_cast<const float4*>(src);
            swt[j4 * 4 + 0][c] = v.x;
            swt[j4 * 4 + 1][c] = v.y;
            swt[j4 * 4 + 2][c] = v.z;
            swt[j4 * 4 + 3][c] = v.w;
        }
        __syncthreads();
#pragma unroll 4
        for (int j = 0; j < 64; j++) {
            float4 wv = *reinterpret_cast<const float4*>(&swt[j][c4]);
            float4 xa = *reinterpret_cast<const float4*>(&sxt[j][rl]);
            float4 xb = *reinterpret_cast<const float4*>(&sxt[j][rl + 4]);
            float xs[8] = {xa.x, xa.y, xa.z, xa.w, xb.x, xb.y, xb.z, xb.w};
            float wsv[4] = {wv.x, wv.y, wv.z, wv.w};
#pragma unroll
            for (int ri = 0; ri < 8; ri++)
#pragma unroll
                for (int ci = 0; ci < 4; ci++)
                    acc[ri][ci] += xs[ri] * wsv[ci];
        }
    }

    // epilogue: bias + relu + store + fused score
    float4 bv = *reinterpret_cast<const float4*>(bias + c4);
    float pc0 = sp[c4], pc1 = sp[c4 + 1], pc2 = sp[c4 + 2], pc3 = sp[c4 + 3];
    float pr[8];
#pragma unroll
    for (int ri = 0; ri < 8; ri++) {
        int row = r0 + rl + ri;
        float4 hv;
        hv.x = fmaxf(acc[ri][0] + bv.x, 0.f);
        hv.y = fmaxf(acc[ri][1] + bv.y, 0.f);
        hv.z = fmaxf(acc[ri][2] + bv.z, 0.f);
        hv.w = fmaxf(acc[ri][3] + bv.w, 0.f);
        pr[ri] = hv.x * pc0 + hv.y * pc1 + hv.z * pc2 + hv.w * pc3;
        if (row < n)
            *reinterpret_cast<float4*>(h + ((size_t)b * NN + row) * HH + c4) = hv;
    }
#pragma unroll
    for (int ri = 0; ri < 8; ri++) {
#pragma unroll
        for (int off = 16; off; off >>= 1) pr[ri] += __shfl_xor(pr[ri], off);
    }
    if (cg == 0) {
        float inorm = 1.f / snorm;
#pragma unroll
        for (int ri = 0; ri < 8; ri++) {
            int row = r0 + rl + ri;
            if (row < n) {
                float sc = tanhf(pr[ri] * inorm);
                unsigned u = __float_as_uint(sc);
                u = (u & 0x80000000u) ? ~u : (u ^ 0x80000000u);   // monotone asc
                u = ~u;                                            // -> descending
                keys[(size_t)b * NN + row] = ((unsigned long long)u << 32) | (unsigned)row;
                ssc[(size_t)b * NN + row] = sc;
            }
        }
    }
}

// ---------------- exact rank via all-pairs compare (keys unique) ----------------
__global__ __launch_bounds__(256) void rank_kernel(
    const unsigned long long* __restrict__ keys, const float* __restrict__ ssc,
    int n, int k, int* __restrict__ perm, float* __restrict__ vals,
    int* __restrict__ inv) {
    __shared__ unsigned long long sk[NN];
    int b = blockIdx.y;
    for (int i = threadIdx.x; i < NN; i += 256) sk[i] = keys[(size_t)b * NN + i];
    __syncthreads();
    int i = blockIdx.x * 256 + threadIdx.x;
    unsigned long long my = sk[i];
    int rank = 0;
#pragma unroll 8
    for (int j = 0; j < NN; j++) rank += (sk[j] < my) ? 1 : 0;
    if (i < n) {
        if (rank < k) {
            perm[b * NN + rank] = i;
            vals[b * NN + rank] = ssc[(size_t)b * NN + i];
            inv[b * NN + i] = rank;
        } else {
            inv[b * NN + i] = -1;
        }
    }
}

// ---------------- x_new[i] = h[perm[i]] * vals[i] ----------------
__global__ void gather_kernel(const float* __restrict__ hin,
                              float* __restrict__ xout,
                              const int* __restrict__ perm,
                              const float* __restrict__ vals, int k) {
    int t = blockIdx.x * blockDim.x + threadIdx.x;
    int total = BB * k * 32;
    if (t >= total) return;
    int c = t & 31;
    int rem = t >> 5;
    int i = rem % k;
    int b = rem / k;
    int pi = perm[b * NN + i];
    float v = vals[b * NN + i];
    float4 x4 = *reinterpret_cast<const float4*>(hin + ((size_t)b * NN + pi) * HH + c * 4);
    float4 o4 = make_float4(x4.x * v, x4.y * v, x4.z * v, x4.w * v);
    *reinterpret_cast<float4*>(xout + ((size_t)b * NN + i) * HH + c * 4) = o4;
}

// ---------------- readout: stage 1 partials (16 blocks/graph) ----------------
__global__ __launch_bounds__(128) void readout_part_kernel(
    const float* __restrict__ x, int k, float* __restrict__ part) {
    int b = blockIdx.x >> 4;
    int j = blockIdx.x & 15;
    int f = threadIdx.x;
    float mx = -INFINITY, sm = 0.f;
    for (int i = j; i < k; i += 16) {
        float v = x[((size_t)b * NN + i) * HH + f];
        mx = fmaxf(mx, v);
        sm += v;
    }
    part[(size_t)blockIdx.x * 256 + f] = mx;
    part[(size_t)blockIdx.x * 256 + 128 + f] = sm;
}

// ---------------- readout: combine + accumulate into r ----------------
__global__ __launch_bounds__(128) void readout_comb_kernel(
    const float* __restrict__ part, float* __restrict__ r, int k) {
    int b = blockIdx.x;
    int f = threadIdx.x;
    float mx = -INFINITY, sm = 0.f;
    for (int j = 0; j < 16; j++) {
        mx = fmaxf(mx, part[((size_t)b * 16 + j) * 256 + f]);
        sm += part[((size_t)b * 16 + j) * 256 + 128 + f];
    }
    r[b * 256 + f] += mx;
    r[b * 256 + 128 + f] += sm / (float)k;
}

// ---------------- edge remap through inv; -1 marks invalid ----------------
__global__ void remap_kernel(const int* __restrict__ inv,
                             const int* __restrict__ sin_,
                             const int* __restrict__ din_,
                             int in_stride,
                             int* __restrict__ sout, int* __restrict__ dout) {
    int t = blockIdx.x * blockDim.x + threadIdx.x;   // B*E
    int e = t & (EE - 1);
    int b = t >> 15;
    if (b >= BB) return;
    int s = sin_[(size_t)b * in_stride + e];
    int d = din_[(size_t)b * in_stride + e];
    int ns = -1, nd = -1;
    if (s >= 0 && d >= 0) {
        ns = inv[b * NN + s];
        nd = inv[b * NN + d];
    }
    if (ns < 0 || nd < 0) { ns = -1; nd = -1; }
    sout[b * EE + e] = ns;
    dout[b * EE + e] = nd;
}

// ---------------- final MLP per graph ----------------
__global__ __launch_bounds__(256) void mlp_kernel(
    const float* __restrict__ r,
    const float* __restrict__ W1, const float* __restrict__ b1,
    const float* __restrict__ W2, const float* __restrict__ b2,
    const float* __restrict__ W3, const float* __restrict__ b3,
    float* __restrict__ out) {
    __shared__ float sg[256];
    __shared__ float s1[128];
    __shared__ float s2[64];
    int b = blockIdx.x, tid = threadIdx.x;
    sg[tid] = r[b * 256 + tid];
    __syncthreads();
    if (tid < 128) {
        float a = b1[tid];
        for (int j = 0; j < 256; j++) a += sg[j] * W1[tid * 256 + j];
        s1[tid] = fmaxf(a, 0.f);
    }
    __syncthreads();
    if (tid < 64) {
        float a = b2[tid];
        for (int j = 0; j < 128; j++) a += s1[j] * W2[tid * 128 + j];
        s2[tid] = fmaxf(a, 0.f);
    }
    __syncthreads();
    if (tid == 0) {
        float a = b3[0];
        for (int j = 0; j < 64; j++) a += s2[j] * W3[j];
        out[b] = 1.f / (1.f + expf(-a));
    }
}

extern "C" void kernel_launch(void* const* d_in, const int* in_sizes, int n_in,
                              void* d_out, int out_size, void* d_ws, size_t ws_size,
                              hipStream_t stream) {
    const float* x   = (const float*)d_in[0];
    const int*   ei  = (const int*)d_in[1];
    const float* Wr1 = (const float*)d_in[2];
    const float* Wl1 = (const float*)d_in[3];
    const float* b1  = (const float*)d_in[4];
    const float* p1  = (const float*)d_in[5];
    const float* Wr2 = (const float*)d_in[6];
    const float* Wl2 = (const float*)d_in[7];
    const float* b2  = (const float*)d_in[8];
    const float* p2  = (const float*)d_in[9];
    const float* Wr3 = (const float*)d_in[10];
    const float* Wl3 = (const float*)d_in[11];
    const float* b3  = (const float*)d_in[12];
    const float* p3  = (const float*)d_in[13];
    const float* l1W = (const float*)d_in[14];
    const float* l1b = (const float*)d_in[15];
    const float* l2W = (const float*)d_in[16];
    const float* l2b = (const float*)d_in[17];
    const float* l3W = (const float*)d_in[18];
    const float* l3b = (const float*)d_in[19];
    float* out = (float*)d_out;

    char* ws = (char*)d_ws;
    float* bufA = (float*)ws; ws += (size_t)BB * NN * HH * 4;
    float* bufB = (float*)ws; ws += (size_t)BB * NN * HH * 4;
    float* agg  = (float*)ws; ws += (size_t)BB * NN * HH * 4;
    int*   perm = (int*)ws;   ws += (size_t)BB * NN * 4;
    float* vals = (float*)ws; ws += (size_t)BB * NN * 4;
    int*   inv  = (int*)ws;   ws += (size_t)BB * NN * 4;
    int*   curS = (int*)ws;   ws += (size_t)BB * EE * 4;
    int*   curD = (int*)ws;   ws += (size_t)BB * EE * 4;
    float* rbuf = (float*)ws; ws += (size_t)BB * 256 * 4;
    float* part = (float*)ws; ws += (size_t)BB * 16 * 256 * 4;
    int*   deg  = (int*)ws;   ws += (size_t)BB * NN * 4;
    int*   rowptr = (int*)ws; ws += (size_t)BB * (NN + 1) * 4;
    int*   cursor = (int*)ws; ws += (size_t)BB * (NN + 1) * 4;
    unsigned long long* keys = (unsigned long long*)ws; ws += (size_t)BB * NN * 8;
    float* ssc  = (float*)ws; ws += (size_t)BB * NN * 4;
    // CSR source array lives in bufA: in every layer, CSR build + aggregation
    // complete BEFORE conv writes bufA, and CSR is dead afterwards.
    int*   csr = (int*)bufA;

    hipMemsetAsync(rbuf, 0, BB * 256 * 4, stream);

    // ---------- layer 1 ----------
    hipMemsetAsync(deg, 0, (size_t)BB * NN * 4, stream);
    hipLaunchKernelGGL(csr_count_kernel, dim3(BB * EE / 256), dim3(256), 0, stream, ei + EE, 2 * EE, deg);
    hipLaunchKernelGGL(csr_scan_kernel, dim3(BB), dim3(1024), 0, stream, deg, rowptr, cursor);
    hipLaunchKernelGGL(csr_fill_kernel, dim3(BB * EE / 256), dim3(256), 0, stream, ei, ei + EE, 2 * EE, cursor, csr);
    hipLaunchKernelGGL(agg1_csr_kernel, dim3(NN / 8, BB), dim3(256), 0, stream, x, rowptr, csr, agg);
    hipLaunchKernelGGL((conv_fused_kernel<FIN>), dim3(NN / 64, BB), dim3(256), 0, stream,
                       x, agg, Wr1, Wl1, b1, p1, bufA, keys, ssc, NN);
    hipLaunchKernelGGL(rank_kernel, dim3(NN / 256, BB), dim3(256), 0, stream, keys, ssc, NN, KK1, perm, vals, inv);
    {
        int tot = BB * KK1 * 32;
        hipLaunchKernelGGL(gather_kernel, dim3((tot + 255) / 256), dim3(256), 0, stream, bufA, bufB, perm, vals, KK1);
    }
    hipLaunchKernelGGL(readout_part_kernel, dim3(BB * 16), dim3(128), 0, stream, bufB, KK1, part);
    hipLaunchKernelGGL(readout_comb_kernel, dim3(BB), dim3(128), 0, stream, part, rbuf, KK1);
    hipLaunchKernelGGL(remap_kernel, dim3(BB * EE / 256), dim3(256), 0, stream, inv, ei, ei + EE, 2 * EE, curS, curD);

    // ---------- layer 2 ----------
    hipMemsetAsync(deg, 0, (size_t)BB * NN * 4, stream);
    hipMemsetAsync(keys, 0xFF, (size_t)BB * NN * 8, stream);
    hipLaunchKernelGGL(csr_count_kernel, dim3(BB * EE / 256), dim3(256), 0, stream, curD, EE, deg);
    hipLaunchKernelGGL(csr_scan_kernel, dim3(BB), dim3(1024), 0, stream, deg, rowptr, cursor);
    hipLaunchKernelGGL(csr_fill_kernel, dim3(BB * EE / 256), dim3(256), 0, stream, curS, curD, EE, cursor, csr);
    hipLaunchKernelGGL(agg23_csr_kernel, dim3((KK1 + 3) / 4, BB), dim3(128), 0, stream, bufB, rowptr, csr, agg, KK1);
    hipLaunchKernelGGL((conv_fused_kernel<HH>), dim3((KK1 + 63) / 64, BB), dim3(256), 0, stream,
                       bufB, agg, Wr2, Wl2, b2, p2, bufA, keys, ssc, KK1);
    hipLaunchKernelGGL(rank_kernel, dim3(NN / 256, BB), dim3(256), 0, stream, keys, ssc, KK1, KK2, perm, vals, inv);
    {
        int tot = BB * KK2 * 32;
        hipLaunchKernelGGL(gather_kernel, dim3((tot + 255) / 256), dim3(256), 0, stream, bufA, bufB, perm, vals, KK2);
    }
    hipLaunchKernelGGL(readout_part_kernel, dim3(BB * 16), dim3(128), 0, stream, bufB, KK2, part);
    hipLaunchKernelGGL(readout_comb_kernel, dim3(BB), dim3(128), 0, stream, part, rbuf, KK2);
    hipLaunchKernelGGL(remap_kernel, dim3(BB * EE / 256), dim3(256), 0, stream, inv, curS, curD, EE, curS, curD);

    // ---------- layer 3 ----------
    hipMemsetAsync(deg, 0, (size_t)BB * NN * 4, stream);
    hipMemsetAsync(keys, 0xFF, (size_t)BB * NN * 8, stream);
    hipLaunchKernelGGL(csr_count_kernel, dim3(BB * EE / 256), dim3(256), 0, stream, curD, EE, deg);
    hipLaunchKernelGGL(csr_scan_kernel, dim3(BB), dim3(1024), 0, stream, deg, rowptr, cursor);
    hipLaunchKernelGGL(csr_fill_kernel, dim3(BB * EE / 256), dim3(256), 0, stream, curS, curD, EE, cursor, csr);
    hipLaunchKernelGGL(agg23_csr_kernel, dim3((KK2 + 3) / 4, BB), dim3(128), 0, stream, bufB, rowptr, csr, agg, KK2);
    hipLaunchKernelGGL((conv_fused_kernel<HH>), dim3((KK2 + 63) / 64, BB), dim3(256), 0, stream,
                       bufB, agg, Wr3, Wl3, b3, p3, bufA, keys, ssc, KK2);
    hipLaunchKernelGGL(rank_kernel, dim3(NN / 256, BB), dim3(256), 0, stream, keys, ssc, KK2, KK3, perm, vals, inv);
    {
        int tot = BB * KK3 * 32;
        hipLaunchKernelGGL(gather_kernel, dim3((tot + 255) / 256), dim3(256), 0, stream, bufA, bufB, perm, vals, KK3);
    }
    hipLaunchKernelGGL(readout_part_kernel, dim3(BB * 16), dim3(128), 0, stream, bufB, KK3, part);
    hipLaunchKernelGGL(readout_comb_kernel, dim3(BB), dim3(128), 0, stream, part, rbuf, KK3);

    // ---------- final MLP ----------
    hipLaunchKernelGGL(mlp_kernel, dim3(BB), dim3(256), 0, stream, rbuf,
                       l1W, l1b, l2W, l2b, l3W, l3b, out);
}